// Round 4
// baseline (2939.650 us; speedup 1.0000x reference)
//
#include <hip/hip_runtime.h>
#include <math.h>

#define N_ATOMS 60000
#define M_NBR   12
#define D_FEA   64
#define NBR_FEA 41
#define B_CRY   1200
#define NA_CRY  50
#define EPSV    1e-5f

#define NBLK_MAIN 2048   // blocks for k_stats / k_reduce (4 waves each)

__device__ __forceinline__ float wsum(float v){
#pragma unroll
  for (int o = 32; o > 0; o >>= 1) v += __shfl_xor(v, o, 64);
  return v;
}
__device__ __forceinline__ float wmax64(float v){
#pragma unroll
  for (int o = 32; o > 0; o >>= 1) v = fmaxf(v, __shfl_xor(v, o, 64));
  return v;
}
__device__ __forceinline__ float softplusf(float x){
  return fmaxf(x, 0.f) + __logf(1.f + __expf(-fabsf(x)));
}
__device__ __forceinline__ float sigmoidf(float x){
  return 1.f / (1.f + __expf(-x));
}

// ---------------- K1: per-crystal graph transformer -> atom_tf [N,64] -------
__global__ __launch_bounds__(256) void k_transformer(
    const float* __restrict__ atom_in, const float* __restrict__ adj,
    const float* __restrict__ w1, const float* __restrict__ b1,
    const float* __restrict__ w2, const float* __restrict__ b2,
    const float* __restrict__ g1v, const float* __restrict__ be1,
    const float* __restrict__ g2v, const float* __restrict__ be2,
    const int* __restrict__ cidx, float* __restrict__ atom_tf)
{
  __shared__ float s_src[NA_CRY * D_FEA];   // current "src" rows
  __shared__ float s_srcT[D_FEA * NA_CRY];  // transposed copy (bank-conflict fix for scores)
  __shared__ float s_sc[NA_CRY * NA_CRY];   // scores / attn
  __shared__ float s_x[NA_CRY * D_FEA];     // temp
  __shared__ float s_y[NA_CRY * D_FEA];     // temp
  __shared__ float s_w[D_FEA * D_FEA];      // weight staging

  const int tid  = threadIdx.x;
  const int b    = blockIdx.x;
  const int lane = tid & 63;
  const int w    = tid >> 6;

  // load src (gather by crystal_atom_idx) + transpose copy
  for (int p = tid; p < NA_CRY * D_FEA; p += 256){
    int i = p >> 6, d = p & 63;
    int a = cidx[b * NA_CRY + i];
    float v = atom_in[a * D_FEA + d];
    s_src[p] = v;
    s_srcT[d * NA_CRY + i] = v;
  }
  __syncthreads();

  // scores = (src . src^T) * scale * adj
  const float scale = 0.125f; // 1/sqrt(64)
  for (int p = tid; p < NA_CRY * NA_CRY; p += 256){
    int i = p / NA_CRY;
    int jj = p - i * NA_CRY;
    float acc = 0.f;
#pragma unroll 8
    for (int d = 0; d < D_FEA; ++d)
      acc += s_src[i * D_FEA + d] * s_srcT[d * NA_CRY + jj];
    s_sc[p] = acc * scale * adj[b * NA_CRY * NA_CRY + p];
  }
  __syncthreads();

  // softmax over rows (wave per row, lanes 0..49 hold the row)
  for (int r = w; r < NA_CRY; r += 4){
    float v = (lane < NA_CRY) ? s_sc[r * NA_CRY + lane] : -1e30f;
    float mx = wmax64(v);
    float e = (lane < NA_CRY) ? __expf(v - mx) : 0.f;
    float s = wsum(e);
    if (lane < NA_CRY) s_sc[r * NA_CRY + lane] = e / s;
  }
  __syncthreads();

  // src2 = attn @ src ; residual into s_x
  for (int p = tid; p < NA_CRY * D_FEA; p += 256){
    int n = p >> 6, d = p & 63;
    float acc = 0.f;
#pragma unroll 10
    for (int m = 0; m < NA_CRY; ++m)
      acc += s_sc[n * NA_CRY + m] * s_src[m * D_FEA + d];
    s_x[p] = s_src[p] + acc;
  }
  __syncthreads();

  // LayerNorm1 -> s_src (wave per row, lane = channel)
  for (int r = w; r < NA_CRY; r += 4){
    float x = s_x[r * D_FEA + lane];
    float mu = wsum(x) * (1.f / 64.f);
    float dx = x - mu;
    float var = wsum(dx * dx) * (1.f / 64.f);
    s_src[r * D_FEA + lane] = dx * rsqrtf(var + EPSV) * g1v[lane] + be1[lane];
  }
  __syncthreads();

  // h1 = relu(src @ w1 + b1)
  for (int p = tid; p < D_FEA * D_FEA; p += 256) s_w[p] = w1[p];
  __syncthreads();
  for (int p = tid; p < NA_CRY * D_FEA; p += 256){
    int n = p >> 6, d = p & 63;
    float acc = b1[d];
#pragma unroll 8
    for (int k = 0; k < D_FEA; ++k)
      acc += s_src[n * D_FEA + k] * s_w[k * D_FEA + d];
    s_y[p] = fmaxf(acc, 0.f);
  }
  __syncthreads();
  // h2 = h1 @ w2 + b2 ; residual
  for (int p = tid; p < D_FEA * D_FEA; p += 256) s_w[p] = w2[p];
  __syncthreads();
  for (int p = tid; p < NA_CRY * D_FEA; p += 256){
    int n = p >> 6, d = p & 63;
    float acc = b2[d];
#pragma unroll 8
    for (int k = 0; k < D_FEA; ++k)
      acc += s_y[n * D_FEA + k] * s_w[k * D_FEA + d];
    s_x[p] = s_src[p] + acc;
  }
  __syncthreads();

  // LayerNorm2 -> atom_tf (row index = b*50 + r, matches src.reshape(N,D))
  for (int r = w; r < NA_CRY; r += 4){
    float x = s_x[r * D_FEA + lane];
    float mu = wsum(x) * (1.f / 64.f);
    float dx = x - mu;
    float var = wsum(dx * dx) * (1.f / 64.f);
    atom_tf[(b * NA_CRY + r) * D_FEA + lane] =
        dx * rsqrtf(var + EPSV) * g2v[lane] + be2[lane];
  }
}

// ---------------- K2: proj1 = atom_tf @ W[0:64] + fc_b ; proj2 = atom_in @ W[64:128]
__global__ __launch_bounds__(256) void k_proj(
    const float* __restrict__ atom_in, const float* __restrict__ atom_tf,
    const float* __restrict__ fc_w, const float* __restrict__ fc_b,
    float* __restrict__ proj1, float* __restrict__ proj2)
{
  __shared__ float sW1[64 * 128];
  __shared__ float sW2[64 * 128];
  const int tid = threadIdx.x, lane = tid & 63, w = tid >> 6;
  for (int p = tid; p < 64 * 128; p += 256){
    sW1[p] = fc_w[p];
    sW2[p] = fc_w[64 * 128 + p];
  }
  __syncthreads();
  const float bias0 = fc_b[lane], bias1 = fc_b[64 + lane];
  const int wg = blockIdx.x * 4 + w, nw = gridDim.x * 4;
  for (int a = wg; a < N_ATOMS; a += nw){
    float t1 = atom_tf[a * 64 + lane];
    float t2 = atom_in[a * 64 + lane];
    float p10 = bias0, p11 = bias1, p20 = 0.f, p21 = 0.f;
#pragma unroll
    for (int k = 0; k < 64; ++k){
      float a1 = __shfl(t1, k, 64);
      float a2 = __shfl(t2, k, 64);
      p10 += a1 * sW1[k * 128 + lane];
      p11 += a1 * sW1[k * 128 + 64 + lane];
      p20 += a2 * sW2[k * 128 + lane];
      p21 += a2 * sW2[k * 128 + 64 + lane];
    }
    proj1[a * 128 + lane] = p10;
    proj1[a * 128 + 64 + lane] = p11;
    proj2[a * 128 + lane] = p20;
    proj2[a * 128 + 64 + lane] = p21;
  }
}

// ------ shared row-compute: g = proj1[n] + proj2[j] + nbr_fea[r] @ Wb
// The bond row nbr_fea[r*41 + k] is WAVE-UNIFORM (r same for all lanes):
// readfirstlane(r) makes the base provably uniform -> the 41 feature reads
// become s_load into SGPRs, and the FMA is v_fmac(vdst, sgpr, vgpr).
// NO readlane/shfl needed. (Round-3 bug: __builtin_amdgcn_readlane(float,..)
// is i32-typed -> silent fptosi value conversion, absmax 1.22.)
// wb0 column pinned in 41 VGPRs (asm anchor); wb1 column in LDS via volatile
// pointer (defeats LICM). m-loop NOT unrolled (12x unroll = 256 VGPR spill).

// ---------------- K3: BN1 stats pass (sum / sumsq per channel) --------------
__global__ __launch_bounds__(256, 4) void k_stats(
    const float* __restrict__ nbr_fea, const int* __restrict__ nbr_idx,
    const float* __restrict__ fc_w, const float* __restrict__ proj1,
    const float* __restrict__ proj2, float* __restrict__ part1)
{
  __shared__ float red[1024];
  __shared__ float s_wb1[NBR_FEA * 64];
  const int tid = threadIdx.x, lane = tid & 63, w = tid >> 6;

  float wb0[NBR_FEA];
#pragma unroll
  for (int k = 0; k < NBR_FEA; ++k)
    wb0[k] = fc_w[(128 + k) * 128 + lane];
#pragma unroll
  for (int k = 0; k < NBR_FEA; ++k)
    asm volatile("" : "+v"(wb0[k]));          // pin in VGPRs (non-remat def)

  for (int p = tid; p < NBR_FEA * 64; p += 256){
    int k = p >> 6, c = p & 63;
    s_wb1[p] = fc_w[(128 + k) * 128 + 64 + c];
  }
  __syncthreads();
  volatile const float* wb1 = s_wb1;          // force per-use ds_read (no hoist)

  const int wg = blockIdx.x * 4 + w, nw = gridDim.x * 4;
  float s0 = 0.f, s1 = 0.f, q0 = 0.f, q1 = 0.f;
  for (int a = wg; a < N_ATOMS; a += nw){
    const int au = __builtin_amdgcn_readfirstlane(a);
    float p10 = proj1[(size_t)au * 128 + lane];
    float p11 = proj1[(size_t)au * 128 + 64 + lane];
    int jn = nbr_idx[au * M_NBR];             // prefetch j for m=0
#pragma unroll 1
    for (int m = 0; m < M_NBR; ++m){
      const int r = au * M_NBR + m;
      const int ju = __builtin_amdgcn_readfirstlane(jn);
      if (m + 1 < M_NBR) jn = nbr_idx[r + 1]; // prefetch next j during compute
      const float* frow = nbr_fea + (size_t)r * NBR_FEA;  // uniform base -> s_load
      float g0 = p10 + proj2[(size_t)ju * 128 + lane];
      float g1 = p11 + proj2[(size_t)ju * 128 + 64 + lane];
#pragma unroll
      for (int k = 0; k < NBR_FEA; ++k){
        float aa = frow[k];
        g0 += aa * wb0[k];
        g1 += aa * wb1[k * 64 + lane];
      }
      s0 += g0; q0 += g0 * g0;
      s1 += g1; q1 += g1 * g1;
    }
  }
  red[w * 256 + lane]        = s0;
  red[w * 256 + 64 + lane]   = s1;
  red[w * 256 + 128 + lane]  = q0;
  red[w * 256 + 192 + lane]  = q1;
  __syncthreads();
  float v = red[tid] + red[256 + tid] + red[512 + tid] + red[768 + tid];
  part1[blockIdx.x * 256 + tid] = v;   // [0:128]=sum(ch), [128:256]=sumsq(ch)
}

// finish BN1 stats: stats1[c]=scale, stats1[128+c]=shift
__global__ __launch_bounds__(1024) void k_stats_fin(
    const float* __restrict__ part1, const float* __restrict__ bn1_g,
    const float* __restrict__ bn1_b, float* __restrict__ stats1)
{
  __shared__ float red2[4 * 256];
  __shared__ float col[256];
  const int tid = threadIdx.x;
  const int c = tid & 255, g = tid >> 8;  // 4 groups
  float v = 0.f;
  for (int b = g; b < NBLK_MAIN; b += 4) v += part1[b * 256 + c];
  red2[g * 256 + c] = v;
  __syncthreads();
  if (g == 0) col[c] = red2[c] + red2[256 + c] + red2[512 + c] + red2[768 + c];
  __syncthreads();
  if (tid < 128){
    const float inv = 1.f / (float)(N_ATOMS * M_NBR);
    float mu = col[tid] * inv;
    float var = col[128 + tid] * inv - mu * mu;
    float sc = bn1_g[tid] * rsqrtf(var + EPSV);
    stats1[tid] = sc;
    stats1[128 + tid] = bn1_b[tid] - mu * sc;
  }
}

// ---------------- K4: recompute g, BN1-normalize, gate, sum over M ----------
__global__ __launch_bounds__(256, 4) void k_reduce(
    const float* __restrict__ nbr_fea, const int* __restrict__ nbr_idx,
    const float* __restrict__ fc_w, const float* __restrict__ proj1,
    const float* __restrict__ proj2, const float* __restrict__ stats1,
    float* __restrict__ nbr_sumed, float* __restrict__ part2)
{
  __shared__ float red[512];
  __shared__ float s_wb1[NBR_FEA * 64];
  const int tid = threadIdx.x, lane = tid & 63, w = tid >> 6;

  float wb0[NBR_FEA];
#pragma unroll
  for (int k = 0; k < NBR_FEA; ++k)
    wb0[k] = fc_w[(128 + k) * 128 + lane];
#pragma unroll
  for (int k = 0; k < NBR_FEA; ++k)
    asm volatile("" : "+v"(wb0[k]));

  for (int p = tid; p < NBR_FEA * 64; p += 256){
    int k = p >> 6, c = p & 63;
    s_wb1[p] = fc_w[(128 + k) * 128 + 64 + c];
  }
  __syncthreads();
  volatile const float* wb1 = s_wb1;

  const float sc0 = stats1[lane],      sc1 = stats1[64 + lane];
  const float tc0 = stats1[128 + lane], tc1 = stats1[192 + lane];
  const int wg = blockIdx.x * 4 + w, nw = gridDim.x * 4;
  float bs = 0.f, bq = 0.f;
  for (int a = wg; a < N_ATOMS; a += nw){
    const int au = __builtin_amdgcn_readfirstlane(a);
    float p10 = proj1[(size_t)au * 128 + lane];
    float p11 = proj1[(size_t)au * 128 + 64 + lane];
    float acc = 0.f;
    int jn = nbr_idx[au * M_NBR];
#pragma unroll 1
    for (int m = 0; m < M_NBR; ++m){
      const int r = au * M_NBR + m;
      const int ju = __builtin_amdgcn_readfirstlane(jn);
      if (m + 1 < M_NBR) jn = nbr_idx[r + 1];
      const float* frow = nbr_fea + (size_t)r * NBR_FEA;
      float g0 = p10 + proj2[(size_t)ju * 128 + lane];
      float g1 = p11 + proj2[(size_t)ju * 128 + 64 + lane];
#pragma unroll
      for (int k = 0; k < NBR_FEA; ++k){
        float aa = frow[k];
        g0 += aa * wb0[k];
        g1 += aa * wb1[k * 64 + lane];
      }
      acc += sigmoidf(g0 * sc0 + tc0) * softplusf(g1 * sc1 + tc1);
    }
    nbr_sumed[(size_t)a * 64 + lane] = acc;
    bs += acc; bq += acc * acc;
  }
  red[w * 128 + lane]      = bs;
  red[w * 128 + 64 + lane] = bq;
  __syncthreads();
  if (tid < 128){
    float v = red[tid] + red[128 + tid] + red[256 + tid] + red[384 + tid];
    part2[blockIdx.x * 128 + tid] = v;  // [0:64]=sum, [64:128]=sumsq
  }
}

// finish BN2 stats
__global__ __launch_bounds__(1024) void k_red_fin(
    const float* __restrict__ part2, const float* __restrict__ bn2_g,
    const float* __restrict__ bn2_b, float* __restrict__ stats2)
{
  __shared__ float red2[8 * 128];
  __shared__ float col[128];
  const int tid = threadIdx.x;
  const int c = tid & 127, g = tid >> 7;  // 8 groups
  float v = 0.f;
  for (int b = g; b < NBLK_MAIN; b += 8) v += part2[b * 128 + c];
  red2[g * 128 + c] = v;
  __syncthreads();
  if (g == 0){
    float t = 0.f;
#pragma unroll
    for (int gg = 0; gg < 8; ++gg) t += red2[gg * 128 + c];
    col[c] = t;
  }
  __syncthreads();
  if (tid < 64){
    const float inv = 1.f / (float)N_ATOMS;
    float mu = col[tid] * inv;
    float var = col[64 + tid] * inv - mu * mu;
    float sc = bn2_g[tid] * rsqrtf(var + EPSV);
    stats2[tid] = sc;
    stats2[64 + tid] = bn2_b[tid] - mu * sc;
  }
}

// ---------------- K5: out = softplus(atom_tf + BN2(nbr_sumed)) --------------
__global__ __launch_bounds__(256) void k_final(
    const float* __restrict__ atom_tf, const float* __restrict__ ns,
    const float* __restrict__ stats2, float* __restrict__ out)
{
  int i = blockIdx.x * 256 + threadIdx.x;
  if (i >= N_ATOMS * 64) return;
  int c = i & 63;
  float x = atom_tf[i] + ns[i] * stats2[c] + stats2[64 + c];
  out[i] = softplusf(x);
}

extern "C" void kernel_launch(void* const* d_in, const int* in_sizes, int n_in,
                              void* d_out, int out_size, void* d_ws, size_t ws_size,
                              hipStream_t stream)
{
  const float* atom_in = (const float*)d_in[0];
  const float* nbr_fea = (const float*)d_in[1];
  const float* adj     = (const float*)d_in[2];
  const float* w1 = (const float*)d_in[3];
  const float* b1 = (const float*)d_in[4];
  const float* w2 = (const float*)d_in[5];
  const float* b2 = (const float*)d_in[6];
  const float* tln1_g = (const float*)d_in[7];
  const float* tln1_b = (const float*)d_in[8];
  const float* tln2_g = (const float*)d_in[9];
  const float* tln2_b = (const float*)d_in[10];
  const float* fc_w = (const float*)d_in[11];
  const float* fc_b = (const float*)d_in[12];
  const float* bn1_g = (const float*)d_in[13];
  const float* bn1_b = (const float*)d_in[14];
  const float* bn2_g = (const float*)d_in[15];
  const float* bn2_b = (const float*)d_in[16];
  const int* nbr_idx = (const int*)d_in[17];
  const int* cidx    = (const int*)d_in[18];
  float* out = (float*)d_out;

  float* ws = (float*)d_ws;
  float* atom_tf   = ws;                                  // N*64
  float* proj1     = atom_tf + (size_t)N_ATOMS * 64;      // N*128
  float* proj2     = proj1 + (size_t)N_ATOMS * 128;       // N*128
  float* nbr_sumed = proj2 + (size_t)N_ATOMS * 128;       // N*64
  float* part1     = nbr_sumed + (size_t)N_ATOMS * 64;    // NBLK*256
  float* stats1    = part1 + (size_t)NBLK_MAIN * 256;     // 256
  float* part2     = stats1 + 256;                        // NBLK*128
  float* stats2    = part2 + (size_t)NBLK_MAIN * 128;     // 128

  k_transformer<<<B_CRY, 256, 0, stream>>>(atom_in, adj, w1, b1, w2, b2,
      tln1_g, tln1_b, tln2_g, tln2_b, cidx, atom_tf);
  k_proj<<<1024, 256, 0, stream>>>(atom_in, atom_tf, fc_w, fc_b, proj1, proj2);
  k_stats<<<NBLK_MAIN, 256, 0, stream>>>(nbr_fea, nbr_idx, fc_w, proj1, proj2, part1);
  k_stats_fin<<<1, 1024, 0, stream>>>(part1, bn1_g, bn1_b, stats1);
  k_reduce<<<NBLK_MAIN, 256, 0, stream>>>(nbr_fea, nbr_idx, fc_w, proj1, proj2,
      stats1, nbr_sumed, part2);
  k_red_fin<<<1, 1024, 0, stream>>>(part2, bn2_g, bn2_b, stats2);
  k_final<<<(N_ATOMS * 64 + 255) / 256, 256, 0, stream>>>(atom_tf, nbr_sumed, stats2, out);
}

// Round 5
// 899.083 us; speedup vs baseline: 3.2696x; 3.2696x over previous
//
#include <hip/hip_runtime.h>
#include <math.h>

#define N_ATOMS 60000
#define M_NBR   12
#define D_FEA   64
#define NBR_FEA 41
#define B_CRY   1200
#define NA_CRY  50
#define EPSV    1e-5f

#define NBLK_MAIN 2048   // blocks for k_stats / k_reduce (4 waves each)

__device__ __forceinline__ float wsum(float v){
#pragma unroll
  for (int o = 32; o > 0; o >>= 1) v += __shfl_xor(v, o, 64);
  return v;
}
__device__ __forceinline__ float wmax64(float v){
#pragma unroll
  for (int o = 32; o > 0; o >>= 1) v = fmaxf(v, __shfl_xor(v, o, 64));
  return v;
}
__device__ __forceinline__ float softplusf(float x){
  return fmaxf(x, 0.f) + __logf(1.f + __expf(-fabsf(x)));
}
__device__ __forceinline__ float sigmoidf(float x){
  return 1.f / (1.f + __expf(-x));
}
// round-to-nearest-even fp32 -> bf16 bits (low 16)
__device__ __forceinline__ unsigned bf16_rne(float x){
  unsigned u = __float_as_uint(x);
  return (u + 0x7fffu + ((u >> 16) & 1u)) >> 16;
}

// ---------------- K1: per-crystal graph transformer -> atom_tf [N,64] -------
__global__ __launch_bounds__(256) void k_transformer(
    const float* __restrict__ atom_in, const float* __restrict__ adj,
    const float* __restrict__ w1, const float* __restrict__ b1,
    const float* __restrict__ w2, const float* __restrict__ b2,
    const float* __restrict__ g1v, const float* __restrict__ be1,
    const float* __restrict__ g2v, const float* __restrict__ be2,
    const int* __restrict__ cidx, float* __restrict__ atom_tf)
{
  __shared__ float s_src[NA_CRY * D_FEA];   // current "src" rows
  __shared__ float s_srcT[D_FEA * NA_CRY];  // transposed copy (bank-conflict fix for scores)
  __shared__ float s_sc[NA_CRY * NA_CRY];   // scores / attn
  __shared__ float s_x[NA_CRY * D_FEA];     // temp
  __shared__ float s_y[NA_CRY * D_FEA];     // temp
  __shared__ float s_w[D_FEA * D_FEA];      // weight staging

  const int tid  = threadIdx.x;
  const int b    = blockIdx.x;
  const int lane = tid & 63;
  const int w    = tid >> 6;

  // load src (gather by crystal_atom_idx) + transpose copy
  for (int p = tid; p < NA_CRY * D_FEA; p += 256){
    int i = p >> 6, d = p & 63;
    int a = cidx[b * NA_CRY + i];
    float v = atom_in[a * D_FEA + d];
    s_src[p] = v;
    s_srcT[d * NA_CRY + i] = v;
  }
  __syncthreads();

  // scores = (src . src^T) * scale * adj
  const float scale = 0.125f; // 1/sqrt(64)
  for (int p = tid; p < NA_CRY * NA_CRY; p += 256){
    int i = p / NA_CRY;
    int jj = p - i * NA_CRY;
    float acc = 0.f;
#pragma unroll 8
    for (int d = 0; d < D_FEA; ++d)
      acc += s_src[i * D_FEA + d] * s_srcT[d * NA_CRY + jj];
    s_sc[p] = acc * scale * adj[b * NA_CRY * NA_CRY + p];
  }
  __syncthreads();

  // softmax over rows (wave per row, lanes 0..49 hold the row)
  for (int r = w; r < NA_CRY; r += 4){
    float v = (lane < NA_CRY) ? s_sc[r * NA_CRY + lane] : -1e30f;
    float mx = wmax64(v);
    float e = (lane < NA_CRY) ? __expf(v - mx) : 0.f;
    float s = wsum(e);
    if (lane < NA_CRY) s_sc[r * NA_CRY + lane] = e / s;
  }
  __syncthreads();

  // src2 = attn @ src ; residual into s_x
  for (int p = tid; p < NA_CRY * D_FEA; p += 256){
    int n = p >> 6, d = p & 63;
    float acc = 0.f;
#pragma unroll 10
    for (int m = 0; m < NA_CRY; ++m)
      acc += s_sc[n * NA_CRY + m] * s_src[m * D_FEA + d];
    s_x[p] = s_src[p] + acc;
  }
  __syncthreads();

  // LayerNorm1 -> s_src (wave per row, lane = channel)
  for (int r = w; r < NA_CRY; r += 4){
    float x = s_x[r * D_FEA + lane];
    float mu = wsum(x) * (1.f / 64.f);
    float dx = x - mu;
    float var = wsum(dx * dx) * (1.f / 64.f);
    s_src[r * D_FEA + lane] = dx * rsqrtf(var + EPSV) * g1v[lane] + be1[lane];
  }
  __syncthreads();

  // h1 = relu(src @ w1 + b1)
  for (int p = tid; p < D_FEA * D_FEA; p += 256) s_w[p] = w1[p];
  __syncthreads();
  for (int p = tid; p < NA_CRY * D_FEA; p += 256){
    int n = p >> 6, d = p & 63;
    float acc = b1[d];
#pragma unroll 8
    for (int k = 0; k < D_FEA; ++k)
      acc += s_src[n * D_FEA + k] * s_w[k * D_FEA + d];
    s_y[p] = fmaxf(acc, 0.f);
  }
  __syncthreads();
  // h2 = h1 @ w2 + b2 ; residual
  for (int p = tid; p < D_FEA * D_FEA; p += 256) s_w[p] = w2[p];
  __syncthreads();
  for (int p = tid; p < NA_CRY * D_FEA; p += 256){
    int n = p >> 6, d = p & 63;
    float acc = b2[d];
#pragma unroll 8
    for (int k = 0; k < D_FEA; ++k)
      acc += s_y[n * D_FEA + k] * s_w[k * D_FEA + d];
    s_x[p] = s_src[p] + acc;
  }
  __syncthreads();

  // LayerNorm2 -> atom_tf (row index = b*50 + r, matches src.reshape(N,D))
  for (int r = w; r < NA_CRY; r += 4){
    float x = s_x[r * D_FEA + lane];
    float mu = wsum(x) * (1.f / 64.f);
    float dx = x - mu;
    float var = wsum(dx * dx) * (1.f / 64.f);
    atom_tf[(b * NA_CRY + r) * D_FEA + lane] =
        dx * rsqrtf(var + EPSV) * g2v[lane] + be2[lane];
  }
}

// ---------------- K2: proj1 = atom_tf @ W[0:64] + fc_b ; proj2 = atom_in @ W[64:128]
__global__ __launch_bounds__(256) void k_proj(
    const float* __restrict__ atom_in, const float* __restrict__ atom_tf,
    const float* __restrict__ fc_w, const float* __restrict__ fc_b,
    float* __restrict__ proj1, float* __restrict__ proj2)
{
  __shared__ float sW1[64 * 128];
  __shared__ float sW2[64 * 128];
  const int tid = threadIdx.x, lane = tid & 63, w = tid >> 6;
  for (int p = tid; p < 64 * 128; p += 256){
    sW1[p] = fc_w[p];
    sW2[p] = fc_w[64 * 128 + p];
  }
  __syncthreads();
  const float bias0 = fc_b[lane], bias1 = fc_b[64 + lane];
  const int wg = blockIdx.x * 4 + w, nw = gridDim.x * 4;
  for (int a = wg; a < N_ATOMS; a += nw){
    float t1 = atom_tf[a * 64 + lane];
    float t2 = atom_in[a * 64 + lane];
    float p10 = bias0, p11 = bias1, p20 = 0.f, p21 = 0.f;
#pragma unroll
    for (int k = 0; k < 64; ++k){
      float a1 = __shfl(t1, k, 64);
      float a2 = __shfl(t2, k, 64);
      p10 += a1 * sW1[k * 128 + lane];
      p11 += a1 * sW1[k * 128 + 64 + lane];
      p20 += a2 * sW2[k * 128 + lane];
      p21 += a2 * sW2[k * 128 + 64 + lane];
    }
    proj1[a * 128 + lane] = p10;
    proj1[a * 128 + 64 + lane] = p11;
    proj2[a * 128 + lane] = p20;
    proj2[a * 128 + 64 + lane] = p21;
  }
}

// ------ shared row-compute: g = proj1[n] + proj2[j] + nbr_fea[r] @ Wb
// Weights: each lane's two columns (c=lane, c=lane+64) packed as 41 u32
// (2 x bf16, RNE). Live set ~64 VGPR -> allocator keeps them resident
// (round-1: 12x unroll spilled at 256 VGPR; round-2: fp32 2x41 arrays got
// rematerialized into 82 L1 loads/iter, L1-BW-bound 452us; round-4: asm
// pins spilled to scratch, 4.5GB HBM). Unpack = 1 shl / 1 and per pair.
// Bond row nbr_fea[r*41+k] is wave-uniform -> readfirstlane + s_load.

// ---------------- K3: BN1 stats pass (sum / sumsq per channel) --------------
__global__ __launch_bounds__(256) void k_stats(
    const float* __restrict__ nbr_fea, const int* __restrict__ nbr_idx,
    const float* __restrict__ fc_w, const float* __restrict__ proj1,
    const float* __restrict__ proj2, float* __restrict__ part1)
{
  __shared__ float red[1024];
  const int tid = threadIdx.x, lane = tid & 63, w = tid >> 6;

  unsigned wbp[NBR_FEA];
#pragma unroll
  for (int k = 0; k < NBR_FEA; ++k){
    float w0 = fc_w[(128 + k) * 128 + lane];
    float w1 = fc_w[(128 + k) * 128 + 64 + lane];
    wbp[k] = bf16_rne(w0) | (bf16_rne(w1) << 16);
  }

  const int wg = blockIdx.x * 4 + w, nw = gridDim.x * 4;
  float s0 = 0.f, s1 = 0.f, q0 = 0.f, q1 = 0.f;
  for (int a = wg; a < N_ATOMS; a += nw){
    const int au = __builtin_amdgcn_readfirstlane(a);
    float p10 = proj1[(size_t)au * 128 + lane];
    float p11 = proj1[(size_t)au * 128 + 64 + lane];
    int jn = nbr_idx[au * M_NBR];             // prefetch j for m=0
#pragma unroll 1
    for (int m = 0; m < M_NBR; ++m){
      const int r = au * M_NBR + m;
      const int ju = __builtin_amdgcn_readfirstlane(jn);
      if (m + 1 < M_NBR) jn = nbr_idx[r + 1]; // prefetch next j during compute
      const float* frow = nbr_fea + (size_t)r * NBR_FEA;  // uniform base -> s_load
      float g0 = p10 + proj2[(size_t)ju * 128 + lane];
      float g1 = p11 + proj2[(size_t)ju * 128 + 64 + lane];
#pragma unroll
      for (int k = 0; k < NBR_FEA; ++k){
        float aa = frow[k];
        float w0 = __uint_as_float(wbp[k] << 16);
        float w1 = __uint_as_float(wbp[k] & 0xffff0000u);
        g0 += aa * w0;
        g1 += aa * w1;
      }
      s0 += g0; q0 += g0 * g0;
      s1 += g1; q1 += g1 * g1;
    }
  }
  red[w * 256 + lane]        = s0;
  red[w * 256 + 64 + lane]   = s1;
  red[w * 256 + 128 + lane]  = q0;
  red[w * 256 + 192 + lane]  = q1;
  __syncthreads();
  float v = red[tid] + red[256 + tid] + red[512 + tid] + red[768 + tid];
  part1[blockIdx.x * 256 + tid] = v;   // [0:128]=sum(ch), [128:256]=sumsq(ch)
}

// finish BN1 stats: stats1[c]=scale, stats1[128+c]=shift
__global__ __launch_bounds__(1024) void k_stats_fin(
    const float* __restrict__ part1, const float* __restrict__ bn1_g,
    const float* __restrict__ bn1_b, float* __restrict__ stats1)
{
  __shared__ float red2[4 * 256];
  __shared__ float col[256];
  const int tid = threadIdx.x;
  const int c = tid & 255, g = tid >> 8;  // 4 groups
  float v = 0.f;
  for (int b = g; b < NBLK_MAIN; b += 4) v += part1[b * 256 + c];
  red2[g * 256 + c] = v;
  __syncthreads();
  if (g == 0) col[c] = red2[c] + red2[256 + c] + red2[512 + c] + red2[768 + c];
  __syncthreads();
  if (tid < 128){
    const float inv = 1.f / (float)(N_ATOMS * M_NBR);
    float mu = col[tid] * inv;
    float var = col[128 + tid] * inv - mu * mu;
    float sc = bn1_g[tid] * rsqrtf(var + EPSV);
    stats1[tid] = sc;
    stats1[128 + tid] = bn1_b[tid] - mu * sc;
  }
}

// ---------------- K4: recompute g, BN1-normalize, gate, sum over M ----------
__global__ __launch_bounds__(256) void k_reduce(
    const float* __restrict__ nbr_fea, const int* __restrict__ nbr_idx,
    const float* __restrict__ fc_w, const float* __restrict__ proj1,
    const float* __restrict__ proj2, const float* __restrict__ stats1,
    float* __restrict__ nbr_sumed, float* __restrict__ part2)
{
  __shared__ float red[512];
  const int tid = threadIdx.x, lane = tid & 63, w = tid >> 6;

  unsigned wbp[NBR_FEA];
#pragma unroll
  for (int k = 0; k < NBR_FEA; ++k){
    float w0 = fc_w[(128 + k) * 128 + lane];
    float w1 = fc_w[(128 + k) * 128 + 64 + lane];
    wbp[k] = bf16_rne(w0) | (bf16_rne(w1) << 16);
  }

  const float sc0 = stats1[lane],      sc1 = stats1[64 + lane];
  const float tc0 = stats1[128 + lane], tc1 = stats1[192 + lane];
  const int wg = blockIdx.x * 4 + w, nw = gridDim.x * 4;
  float bs = 0.f, bq = 0.f;
  for (int a = wg; a < N_ATOMS; a += nw){
    const int au = __builtin_amdgcn_readfirstlane(a);
    float p10 = proj1[(size_t)au * 128 + lane];
    float p11 = proj1[(size_t)au * 128 + 64 + lane];
    float acc = 0.f;
    int jn = nbr_idx[au * M_NBR];
#pragma unroll 1
    for (int m = 0; m < M_NBR; ++m){
      const int r = au * M_NBR + m;
      const int ju = __builtin_amdgcn_readfirstlane(jn);
      if (m + 1 < M_NBR) jn = nbr_idx[r + 1];
      const float* frow = nbr_fea + (size_t)r * NBR_FEA;
      float g0 = p10 + proj2[(size_t)ju * 128 + lane];
      float g1 = p11 + proj2[(size_t)ju * 128 + 64 + lane];
#pragma unroll
      for (int k = 0; k < NBR_FEA; ++k){
        float aa = frow[k];
        float w0 = __uint_as_float(wbp[k] << 16);
        float w1 = __uint_as_float(wbp[k] & 0xffff0000u);
        g0 += aa * w0;
        g1 += aa * w1;
      }
      acc += sigmoidf(g0 * sc0 + tc0) * softplusf(g1 * sc1 + tc1);
    }
    nbr_sumed[(size_t)a * 64 + lane] = acc;
    bs += acc; bq += acc * acc;
  }
  red[w * 128 + lane]      = bs;
  red[w * 128 + 64 + lane] = bq;
  __syncthreads();
  if (tid < 128){
    float v = red[tid] + red[128 + tid] + red[256 + tid] + red[384 + tid];
    part2[blockIdx.x * 128 + tid] = v;  // [0:64]=sum, [64:128]=sumsq
  }
}

// finish BN2 stats
__global__ __launch_bounds__(1024) void k_red_fin(
    const float* __restrict__ part2, const float* __restrict__ bn2_g,
    const float* __restrict__ bn2_b, float* __restrict__ stats2)
{
  __shared__ float red2[8 * 128];
  __shared__ float col[128];
  const int tid = threadIdx.x;
  const int c = tid & 127, g = tid >> 7;  // 8 groups
  float v = 0.f;
  for (int b = g; b < NBLK_MAIN; b += 8) v += part2[b * 128 + c];
  red2[g * 128 + c] = v;
  __syncthreads();
  if (g == 0){
    float t = 0.f;
#pragma unroll
    for (int gg = 0; gg < 8; ++gg) t += red2[gg * 128 + c];
    col[c] = t;
  }
  __syncthreads();
  if (tid < 64){
    const float inv = 1.f / (float)N_ATOMS;
    float mu = col[tid] * inv;
    float var = col[64 + tid] * inv - mu * mu;
    float sc = bn2_g[tid] * rsqrtf(var + EPSV);
    stats2[tid] = sc;
    stats2[64 + tid] = bn2_b[tid] - mu * sc;
  }
}

// ---------------- K5: out = softplus(atom_tf + BN2(nbr_sumed)) --------------
__global__ __launch_bounds__(256) void k_final(
    const float* __restrict__ atom_tf, const float* __restrict__ ns,
    const float* __restrict__ stats2, float* __restrict__ out)
{
  int i = blockIdx.x * 256 + threadIdx.x;
  if (i >= N_ATOMS * 64) return;
  int c = i & 63;
  float x = atom_tf[i] + ns[i] * stats2[c] + stats2[64 + c];
  out[i] = softplusf(x);
}

extern "C" void kernel_launch(void* const* d_in, const int* in_sizes, int n_in,
                              void* d_out, int out_size, void* d_ws, size_t ws_size,
                              hipStream_t stream)
{
  const float* atom_in = (const float*)d_in[0];
  const float* nbr_fea = (const float*)d_in[1];
  const float* adj     = (const float*)d_in[2];
  const float* w1 = (const float*)d_in[3];
  const float* b1 = (const float*)d_in[4];
  const float* w2 = (const float*)d_in[5];
  const float* b2 = (const float*)d_in[6];
  const float* tln1_g = (const float*)d_in[7];
  const float* tln1_b = (const float*)d_in[8];
  const float* tln2_g = (const float*)d_in[9];
  const float* tln2_b = (const float*)d_in[10];
  const float* fc_w = (const float*)d_in[11];
  const float* fc_b = (const float*)d_in[12];
  const float* bn1_g = (const float*)d_in[13];
  const float* bn1_b = (const float*)d_in[14];
  const float* bn2_g = (const float*)d_in[15];
  const float* bn2_b = (const float*)d_in[16];
  const int* nbr_idx = (const int*)d_in[17];
  const int* cidx    = (const int*)d_in[18];
  float* out = (float*)d_out;

  float* ws = (float*)d_ws;
  float* atom_tf   = ws;                                  // N*64
  float* proj1     = atom_tf + (size_t)N_ATOMS * 64;      // N*128
  float* proj2     = proj1 + (size_t)N_ATOMS * 128;       // N*128
  float* nbr_sumed = proj2 + (size_t)N_ATOMS * 128;       // N*64
  float* part1     = nbr_sumed + (size_t)N_ATOMS * 64;    // NBLK*256
  float* stats1    = part1 + (size_t)NBLK_MAIN * 256;     // 256
  float* part2     = stats1 + 256;                        // NBLK*128
  float* stats2    = part2 + (size_t)NBLK_MAIN * 128;     // 128

  k_transformer<<<B_CRY, 256, 0, stream>>>(atom_in, adj, w1, b1, w2, b2,
      tln1_g, tln1_b, tln2_g, tln2_b, cidx, atom_tf);
  k_proj<<<1024, 256, 0, stream>>>(atom_in, atom_tf, fc_w, fc_b, proj1, proj2);
  k_stats<<<NBLK_MAIN, 256, 0, stream>>>(nbr_fea, nbr_idx, fc_w, proj1, proj2, part1);
  k_stats_fin<<<1, 1024, 0, stream>>>(part1, bn1_g, bn1_b, stats1);
  k_reduce<<<NBLK_MAIN, 256, 0, stream>>>(nbr_fea, nbr_idx, fc_w, proj1, proj2,
      stats1, nbr_sumed, part2);
  k_red_fin<<<1, 1024, 0, stream>>>(part2, bn2_g, bn2_b, stats2);
  k_final<<<(N_ATOMS * 64 + 255) / 256, 256, 0, stream>>>(atom_tf, nbr_sumed, stats2, out);
}

// Round 6
// 891.229 us; speedup vs baseline: 3.2984x; 1.0088x over previous
//
#include <hip/hip_runtime.h>
#include <math.h>

#define N_ATOMS 60000
#define M_NBR   12
#define D_FEA   64
#define NBR_FEA 41
#define B_CRY   1200
#define NA_CRY  50
#define EPSV    1e-5f

#define NBLK_MAIN 2048   // blocks for k_stats / k_reduce (4 waves each)

__device__ __forceinline__ float wsum(float v){
#pragma unroll
  for (int o = 32; o > 0; o >>= 1) v += __shfl_xor(v, o, 64);
  return v;
}
__device__ __forceinline__ float wmax64(float v){
#pragma unroll
  for (int o = 32; o > 0; o >>= 1) v = fmaxf(v, __shfl_xor(v, o, 64));
  return v;
}
__device__ __forceinline__ float softplusf(float x){
  return fmaxf(x, 0.f) + __logf(1.f + __expf(-fabsf(x)));
}
__device__ __forceinline__ float sigmoidf(float x){
  return 1.f / (1.f + __expf(-x));
}
// round-to-nearest-even fp32 -> bf16 bits (low 16)
__device__ __forceinline__ unsigned bf16_rne(float x){
  unsigned u = __float_as_uint(x);
  return (u + 0x7fffu + ((u >> 16) & 1u)) >> 16;
}

// ---------------- K1: per-crystal graph transformer -> atom_tf [N,64] -------
// LDS diet: 3 aliased buffers (37.8 KiB) -> 4 blocks/CU (was 76 KiB -> 2).
//   s_a   [50*64]  : src, then LN1(src)            (12.8 KiB)
//   s_b   [64*51]  : srcT (pad 51, gcd(51,32)=1 -> no bank conflict);
//                    reused as x = src+src2, then as LN2 input   (13.1 KiB)
//   s_c   [50*64]  : scores/attn (2500 used), reused as h1       (12.8 KiB)
// w1/w2 read directly from global (L1-resident, coalesced) - no staging.
__global__ __launch_bounds__(256, 4) void k_transformer(
    const float* __restrict__ atom_in, const float* __restrict__ adj,
    const float* __restrict__ w1, const float* __restrict__ b1,
    const float* __restrict__ w2, const float* __restrict__ b2,
    const float* __restrict__ g1v, const float* __restrict__ be1,
    const float* __restrict__ g2v, const float* __restrict__ be2,
    const int* __restrict__ cidx, float* __restrict__ atom_tf)
{
  __shared__ float s_a[NA_CRY * D_FEA];        // src / LN1(src)
  __shared__ float s_b[D_FEA * (NA_CRY + 1)];  // srcT(stride 51) / x / LN2-in
  __shared__ float s_c[NA_CRY * D_FEA];        // scores / h1

  const int tid  = threadIdx.x;
  const int b    = blockIdx.x;
  const int lane = tid & 63;
  const int w    = tid >> 6;

  // phase 1: load src (gather) + transposed copy (stride 51)
  for (int p = tid; p < NA_CRY * D_FEA; p += 256){
    int i = p >> 6, d = p & 63;
    int a = cidx[b * NA_CRY + i];
    float v = atom_in[a * D_FEA + d];
    s_a[p] = v;
    s_b[d * (NA_CRY + 1) + i] = v;
  }
  __syncthreads();

  // phase 2: scores = (src . src^T) * scale * adj  -> s_c[0:2500]
  const float scale = 0.125f; // 1/sqrt(64)
  for (int p = tid; p < NA_CRY * NA_CRY; p += 256){
    int i = p / NA_CRY;
    int jj = p - i * NA_CRY;
    float acc = 0.f;
#pragma unroll 8
    for (int d = 0; d < D_FEA; ++d)
      acc += s_a[i * D_FEA + d] * s_b[d * (NA_CRY + 1) + jj];
    s_c[p] = acc * scale * adj[b * NA_CRY * NA_CRY + p];
  }
  __syncthreads();

  // phase 3: softmax over rows (wave per row)
  for (int r = w; r < NA_CRY; r += 4){
    float v = (lane < NA_CRY) ? s_c[r * NA_CRY + lane] : -1e30f;
    float mx = wmax64(v);
    float e = (lane < NA_CRY) ? __expf(v - mx) : 0.f;
    float s = wsum(e);
    if (lane < NA_CRY) s_c[r * NA_CRY + lane] = e / s;
  }
  __syncthreads();

  // phase 4: x = src + attn @ src   (srcT dead -> write x into s_b, linear)
  for (int p = tid; p < NA_CRY * D_FEA; p += 256){
    int n = p >> 6, d = p & 63;
    float acc = 0.f;
#pragma unroll 10
    for (int m = 0; m < NA_CRY; ++m)
      acc += s_c[n * NA_CRY + m] * s_a[m * D_FEA + d];
    float x = s_a[p] + acc;
    __syncthreads();       // ensure all reads of s_a/s_c done before overwrite?
    s_b[p] = x;
    __syncthreads();
  }
  // NOTE: the loop runs at most ceil(3200/256)=13 iterations for every thread
  // (uniform trip count) so the barriers above are convergent; they guarantee
  // s_b's srcT contents are fully consumed before being overwritten. Cheap
  // (13 barriers) and removes the WAR hazard between phase-2 reads and x.

  // phase 5: LN1 -> s_a  (x residual base stays in s_b)
  for (int r = w; r < NA_CRY; r += 4){
    float x = s_b[r * D_FEA + lane];
    float mu = wsum(x) * (1.f / 64.f);
    float dx = x - mu;
    float var = wsum(dx * dx) * (1.f / 64.f);
    s_a[r * D_FEA + lane] = dx * rsqrtf(var + EPSV) * g1v[lane] + be1[lane];
  }
  __syncthreads();

  // phase 6: h1 = relu(LN1 @ w1 + b1) -> s_c (scores dead)
  for (int p = tid; p < NA_CRY * D_FEA; p += 256){
    int n = p >> 6, d = p & 63;
    float acc = b1[d];
#pragma unroll 8
    for (int k = 0; k < D_FEA; ++k)
      acc += s_a[n * D_FEA + k] * w1[k * D_FEA + d];
    s_c[p] = fmaxf(acc, 0.f);
  }
  __syncthreads();

  // phase 7: t = LN1src + h1 @ w2 + b2 -> s_b (x dead after this read? no:
  // residual base is LN1 output s_a, x no longer needed) -> write s_b
  for (int p = tid; p < NA_CRY * D_FEA; p += 256){
    int n = p >> 6, d = p & 63;
    float acc = b2[d];
#pragma unroll 8
    for (int k = 0; k < D_FEA; ++k)
      acc += s_c[n * D_FEA + k] * w2[k * D_FEA + d];
    s_b[p] = s_a[p] + acc;
  }
  __syncthreads();

  // phase 8: LN2 -> atom_tf
  for (int r = w; r < NA_CRY; r += 4){
    float x = s_b[r * D_FEA + lane];
    float mu = wsum(x) * (1.f / 64.f);
    float dx = x - mu;
    float var = wsum(dx * dx) * (1.f / 64.f);
    atom_tf[(b * NA_CRY + r) * D_FEA + lane] =
        dx * rsqrtf(var + EPSV) * g2v[lane] + be2[lane];
  }
}

// ---------------- K2: proj1 = atom_tf @ W[0:64] + fc_b ; proj2 = atom_in @ W[64:128]
__global__ __launch_bounds__(256) void k_proj(
    const float* __restrict__ atom_in, const float* __restrict__ atom_tf,
    const float* __restrict__ fc_w, const float* __restrict__ fc_b,
    float* __restrict__ proj1, float* __restrict__ proj2)
{
  __shared__ float sW1[64 * 128];
  __shared__ float sW2[64 * 128];
  const int tid = threadIdx.x, lane = tid & 63, w = tid >> 6;
  for (int p = tid; p < 64 * 128; p += 256){
    sW1[p] = fc_w[p];
    sW2[p] = fc_w[64 * 128 + p];
  }
  __syncthreads();
  const float bias0 = fc_b[lane], bias1 = fc_b[64 + lane];
  const int wg = blockIdx.x * 4 + w, nw = gridDim.x * 4;
  for (int a = wg; a < N_ATOMS; a += nw){
    float t1 = atom_tf[a * 64 + lane];
    float t2 = atom_in[a * 64 + lane];
    float p10 = bias0, p11 = bias1, p20 = 0.f, p21 = 0.f;
#pragma unroll
    for (int k = 0; k < 64; ++k){
      float a1 = __shfl(t1, k, 64);
      float a2 = __shfl(t2, k, 64);
      p10 += a1 * sW1[k * 128 + lane];
      p11 += a1 * sW1[k * 128 + 64 + lane];
      p20 += a2 * sW2[k * 128 + lane];
      p21 += a2 * sW2[k * 128 + 64 + lane];
    }
    proj1[a * 128 + lane] = p10;
    proj1[a * 128 + 64 + lane] = p11;
    proj2[a * 128 + lane] = p20;
    proj2[a * 128 + 64 + lane] = p21;
  }
}

// ------ shared row-compute: g = proj1[n] + proj2[j] + nbr_fea[r] @ Wb
// Weights: each lane's two columns (c=lane, c=lane+64) packed as 41 u32
// (2 x bf16, RNE) -> live set ~64 VGPR, resident, zero reload traffic.
// Bond row nbr_fea[r*41+k] is wave-uniform -> readfirstlane + s_load.

// ---------------- K3: BN1 stats pass (sum / sumsq per channel) --------------
__global__ __launch_bounds__(256) void k_stats(
    const float* __restrict__ nbr_fea, const int* __restrict__ nbr_idx,
    const float* __restrict__ fc_w, const float* __restrict__ proj1,
    const float* __restrict__ proj2, float* __restrict__ part1)
{
  __shared__ float red[1024];
  const int tid = threadIdx.x, lane = tid & 63, w = tid >> 6;

  unsigned wbp[NBR_FEA];
#pragma unroll
  for (int k = 0; k < NBR_FEA; ++k){
    float w0 = fc_w[(128 + k) * 128 + lane];
    float w1 = fc_w[(128 + k) * 128 + 64 + lane];
    wbp[k] = bf16_rne(w0) | (bf16_rne(w1) << 16);
  }

  const int wg = blockIdx.x * 4 + w, nw = gridDim.x * 4;
  float s0 = 0.f, s1 = 0.f, q0 = 0.f, q1 = 0.f;
  for (int a = wg; a < N_ATOMS; a += nw){
    const int au = __builtin_amdgcn_readfirstlane(a);
    float p10 = proj1[(size_t)au * 128 + lane];
    float p11 = proj1[(size_t)au * 128 + 64 + lane];
    int jn = nbr_idx[au * M_NBR];             // prefetch j for m=0
#pragma unroll 1
    for (int m = 0; m < M_NBR; ++m){
      const int r = au * M_NBR + m;
      const int ju = __builtin_amdgcn_readfirstlane(jn);
      if (m + 1 < M_NBR) jn = nbr_idx[r + 1]; // prefetch next j during compute
      const float* frow = nbr_fea + (size_t)r * NBR_FEA;  // uniform base -> s_load
      float g0 = p10 + proj2[(size_t)ju * 128 + lane];
      float g1 = p11 + proj2[(size_t)ju * 128 + 64 + lane];
#pragma unroll
      for (int k = 0; k < NBR_FEA; ++k){
        float aa = frow[k];
        float w0 = __uint_as_float(wbp[k] << 16);
        float w1 = __uint_as_float(wbp[k] & 0xffff0000u);
        g0 += aa * w0;
        g1 += aa * w1;
      }
      s0 += g0; q0 += g0 * g0;
      s1 += g1; q1 += g1 * g1;
    }
  }
  red[w * 256 + lane]        = s0;
  red[w * 256 + 64 + lane]   = s1;
  red[w * 256 + 128 + lane]  = q0;
  red[w * 256 + 192 + lane]  = q1;
  __syncthreads();
  float v = red[tid] + red[256 + tid] + red[512 + tid] + red[768 + tid];
  part1[blockIdx.x * 256 + tid] = v;   // [0:128]=sum(ch), [128:256]=sumsq(ch)
}

// finish BN1 stats: stats1[c]=scale, stats1[128+c]=shift
__global__ __launch_bounds__(1024) void k_stats_fin(
    const float* __restrict__ part1, const float* __restrict__ bn1_g,
    const float* __restrict__ bn1_b, float* __restrict__ stats1)
{
  __shared__ float red2[4 * 256];
  __shared__ float col[256];
  const int tid = threadIdx.x;
  const int c = tid & 255, g = tid >> 8;  // 4 groups
  float v = 0.f;
  for (int b = g; b < NBLK_MAIN; b += 4) v += part1[b * 256 + c];
  red2[g * 256 + c] = v;
  __syncthreads();
  if (g == 0) col[c] = red2[c] + red2[256 + c] + red2[512 + c] + red2[768 + c];
  __syncthreads();
  if (tid < 128){
    const float inv = 1.f / (float)(N_ATOMS * M_NBR);
    float mu = col[tid] * inv;
    float var = col[128 + tid] * inv - mu * mu;
    float sc = bn1_g[tid] * rsqrtf(var + EPSV);
    stats1[tid] = sc;
    stats1[128 + tid] = bn1_b[tid] - mu * sc;
  }
}

// ---------------- K4: recompute g, BN1-normalize, gate, sum over M ----------
__global__ __launch_bounds__(256) void k_reduce(
    const float* __restrict__ nbr_fea, const int* __restrict__ nbr_idx,
    const float* __restrict__ fc_w, const float* __restrict__ proj1,
    const float* __restrict__ proj2, const float* __restrict__ stats1,
    float* __restrict__ nbr_sumed, float* __restrict__ part2)
{
  __shared__ float red[512];
  const int tid = threadIdx.x, lane = tid & 63, w = tid >> 6;

  unsigned wbp[NBR_FEA];
#pragma unroll
  for (int k = 0; k < NBR_FEA; ++k){
    float w0 = fc_w[(128 + k) * 128 + lane];
    float w1 = fc_w[(128 + k) * 128 + 64 + lane];
    wbp[k] = bf16_rne(w0) | (bf16_rne(w1) << 16);
  }

  const float sc0 = stats1[lane],      sc1 = stats1[64 + lane];
  const float tc0 = stats1[128 + lane], tc1 = stats1[192 + lane];
  const int wg = blockIdx.x * 4 + w, nw = gridDim.x * 4;
  float bs = 0.f, bq = 0.f;
  for (int a = wg; a < N_ATOMS; a += nw){
    const int au = __builtin_amdgcn_readfirstlane(a);
    float p10 = proj1[(size_t)au * 128 + lane];
    float p11 = proj1[(size_t)au * 128 + 64 + lane];
    float acc = 0.f;
    int jn = nbr_idx[au * M_NBR];
#pragma unroll 1
    for (int m = 0; m < M_NBR; ++m){
      const int r = au * M_NBR + m;
      const int ju = __builtin_amdgcn_readfirstlane(jn);
      if (m + 1 < M_NBR) jn = nbr_idx[r + 1];
      const float* frow = nbr_fea + (size_t)r * NBR_FEA;
      float g0 = p10 + proj2[(size_t)ju * 128 + lane];
      float g1 = p11 + proj2[(size_t)ju * 128 + 64 + lane];
#pragma unroll
      for (int k = 0; k < NBR_FEA; ++k){
        float aa = frow[k];
        float w0 = __uint_as_float(wbp[k] << 16);
        float w1 = __uint_as_float(wbp[k] & 0xffff0000u);
        g0 += aa * w0;
        g1 += aa * w1;
      }
      acc += sigmoidf(g0 * sc0 + tc0) * softplusf(g1 * sc1 + tc1);
    }
    nbr_sumed[(size_t)a * 64 + lane] = acc;
    bs += acc; bq += acc * acc;
  }
  red[w * 128 + lane]      = bs;
  red[w * 128 + 64 + lane] = bq;
  __syncthreads();
  if (tid < 128){
    float v = red[tid] + red[128 + tid] + red[256 + tid] + red[384 + tid];
    part2[blockIdx.x * 128 + tid] = v;  // [0:64]=sum, [64:128]=sumsq
  }
}

// finish BN2 stats
__global__ __launch_bounds__(1024) void k_red_fin(
    const float* __restrict__ part2, const float* __restrict__ bn2_g,
    const float* __restrict__ bn2_b, float* __restrict__ stats2)
{
  __shared__ float red2[8 * 128];
  __shared__ float col[128];
  const int tid = threadIdx.x;
  const int c = tid & 127, g = tid >> 7;  // 8 groups
  float v = 0.f;
  for (int b = g; b < NBLK_MAIN; b += 8) v += part2[b * 128 + c];
  red2[g * 128 + c] = v;
  __syncthreads();
  if (g == 0){
    float t = 0.f;
#pragma unroll
    for (int gg = 0; gg < 8; ++gg) t += red2[gg * 128 + c];
    col[c] = t;
  }
  __syncthreads();
  if (tid < 64){
    const float inv = 1.f / (float)N_ATOMS;
    float mu = col[tid] * inv;
    float var = col[64 + tid] * inv - mu * mu;
    float sc = bn2_g[tid] * rsqrtf(var + EPSV);
    stats2[tid] = sc;
    stats2[64 + tid] = bn2_b[tid] - mu * sc;
  }
}

// ---------------- K5: out = softplus(atom_tf + BN2(nbr_sumed)) --------------
__global__ __launch_bounds__(256) void k_final(
    const float* __restrict__ atom_tf, const float* __restrict__ ns,
    const float* __restrict__ stats2, float* __restrict__ out)
{
  int i = blockIdx.x * 256 + threadIdx.x;
  if (i >= N_ATOMS * 64) return;
  int c = i & 63;
  float x = atom_tf[i] + ns[i] * stats2[c] + stats2[64 + c];
  out[i] = softplusf(x);
}

extern "C" void kernel_launch(void* const* d_in, const int* in_sizes, int n_in,
                              void* d_out, int out_size, void* d_ws, size_t ws_size,
                              hipStream_t stream)
{
  const float* atom_in = (const float*)d_in[0];
  const float* nbr_fea = (const float*)d_in[1];
  const float* adj     = (const float*)d_in[2];
  const float* w1 = (const float*)d_in[3];
  const float* b1 = (const float*)d_in[4];
  const float* w2 = (const float*)d_in[5];
  const float* b2 = (const float*)d_in[6];
  const float* tln1_g = (const float*)d_in[7];
  const float* tln1_b = (const float*)d_in[8];
  const float* tln2_g = (const float*)d_in[9];
  const float* tln2_b = (const float*)d_in[10];
  const float* fc_w = (const float*)d_in[11];
  const float* fc_b = (const float*)d_in[12];
  const float* bn1_g = (const float*)d_in[13];
  const float* bn1_b = (const float*)d_in[14];
  const float* bn2_g = (const float*)d_in[15];
  const float* bn2_b = (const float*)d_in[16];
  const int* nbr_idx = (const int*)d_in[17];
  const int* cidx    = (const int*)d_in[18];
  float* out = (float*)d_out;

  float* ws = (float*)d_ws;
  float* atom_tf   = ws;                                  // N*64
  float* proj1     = atom_tf + (size_t)N_ATOMS * 64;      // N*128
  float* proj2     = proj1 + (size_t)N_ATOMS * 128;       // N*128
  float* nbr_sumed = proj2 + (size_t)N_ATOMS * 128;       // N*64
  float* part1     = nbr_sumed + (size_t)N_ATOMS * 64;    // NBLK*256
  float* stats1    = part1 + (size_t)NBLK_MAIN * 256;     // 256
  float* part2     = stats1 + 256;                        // NBLK*128
  float* stats2    = part2 + (size_t)NBLK_MAIN * 128;     // 128

  k_transformer<<<B_CRY, 256, 0, stream>>>(atom_in, adj, w1, b1, w2, b2,
      tln1_g, tln1_b, tln2_g, tln2_b, cidx, atom_tf);
  k_proj<<<1024, 256, 0, stream>>>(atom_in, atom_tf, fc_w, fc_b, proj1, proj2);
  k_stats<<<NBLK_MAIN, 256, 0, stream>>>(nbr_fea, nbr_idx, fc_w, proj1, proj2, part1);
  k_stats_fin<<<1, 1024, 0, stream>>>(part1, bn1_g, bn1_b, stats1);
  k_reduce<<<NBLK_MAIN, 256, 0, stream>>>(nbr_fea, nbr_idx, fc_w, proj1, proj2,
      stats1, nbr_sumed, part2);
  k_red_fin<<<1, 1024, 0, stream>>>(part2, bn2_g, bn2_b, stats2);
  k_final<<<(N_ATOMS * 64 + 255) / 256, 256, 0, stream>>>(atom_tf, nbr_sumed, stats2, out);
}